// Round 6
// baseline (179.299 us; speedup 1.0000x reference)
//
#include <hip/hip_runtime.h>
#include <hip/hip_bf16.h>

typedef __attribute__((ext_vector_type(8))) short short8;
typedef __attribute__((ext_vector_type(4))) short short4v;
typedef __attribute__((ext_vector_type(4))) float float4v;

#define MFMA16(a, b, c) __builtin_amdgcn_mfma_f32_16x16x32_bf16(a, b, c, 0, 0, 0)

__device__ __forceinline__ short f2bf(float f) {
    __hip_bfloat16 hb = __float2bfloat16(f);
    return *reinterpret_cast<short*>(&hb);
}

// ---------------------------------------------------------------------------
// Kernel 0: W transpose+convert.  W[512][1024] f32 -> Wt[1024][512] bf16.
// grid (16 ctiles, 8 ktiles, 2), block 256.
// ---------------------------------------------------------------------------
__global__ __launch_bounds__(256) void wt_kernel(
    const float* __restrict__ Wn, const float* __restrict__ Wr,
    __hip_bfloat16* __restrict__ Wtn, __hip_bfloat16* __restrict__ Wtr)
{
    const int c0 = blockIdx.x * 64;
    const int k0 = blockIdx.y * 64;
    const int g  = blockIdx.z;
    const float* W = g ? Wr : Wn;
    __hip_bfloat16* Wt = g ? Wtr : Wtn;

    __shared__ short lds[64][72];
    const int t = threadIdx.x;
    {
        const int i  = t >> 2;            // k row
        const int j0 = (t & 3) * 16;      // c chunk
        const float* p = W + (size_t)(k0 + i) * 1024 + c0 + j0;
        #pragma unroll
        for (int jj = 0; jj < 16; ++jj)
            lds[j0 + jj][i] = f2bf(p[jj]);  // lds[c][k]
    }
    __syncthreads();
    {
        const int j  = t >> 2;            // c row
        const int i0 = (t & 3) * 16;      // k chunk
        __hip_bfloat16* q = Wt + (size_t)(c0 + j) * 512 + k0 + i0;
        short8 v0 = *reinterpret_cast<const short8*>(&lds[j][i0]);
        short8 v1 = *reinterpret_cast<const short8*>(&lds[j][i0 + 8]);
        *reinterpret_cast<short8*>(q)     = v0;
        *reinterpret_cast<short8*>(q + 8) = v1;
    }
}

// ---------------------------------------------------------------------------
// Kernel 1: prep.  nv/rv [b][n][512] f32 -> Vt [b][h][64][1024] bf16 (transp.)
//                                        -> Abf [b][n][512] bf16 (straight).
// grid: (32 = 16 ntiles x 2 srcs, 8 h, 8 b), block 256.
// ---------------------------------------------------------------------------
__global__ __launch_bounds__(256) void prep_kernel(
    const float* __restrict__ nv, const float* __restrict__ rv,
    __hip_bfloat16* __restrict__ Vtn, __hip_bfloat16* __restrict__ Vtr,
    __hip_bfloat16* __restrict__ An,  __hip_bfloat16* __restrict__ Ar)
{
    const int ntile = blockIdx.x & 15;
    const int src   = blockIdx.x >> 4;
    const int h     = blockIdx.y;
    const int b     = blockIdx.z;
    const float* V  = src ? rv : nv;
    __hip_bfloat16* Vt = src ? Vtr : Vtn;
    __hip_bfloat16* Ab = src ? Ar  : An;

    __shared__ short lds[64][72];
    const int t  = threadIdx.x;
    const int n0 = ntile * 64;
    {
        const int i  = t >> 2;            // n within tile
        const int j0 = (t & 3) * 16;      // d chunk
        const float* p = V + ((size_t)(b * 1024) + n0 + i) * 512 + h * 64 + j0;
        short8 a0, a1;
        #pragma unroll
        for (int jj = 0; jj < 8; ++jj) {
            short x = f2bf(p[jj]);
            a0[jj] = x; lds[j0 + jj][i] = x;
        }
        #pragma unroll
        for (int jj = 0; jj < 8; ++jj) {
            short x = f2bf(p[8 + jj]);
            a1[jj] = x; lds[j0 + 8 + jj][i] = x;
        }
        __hip_bfloat16* adst = Ab + ((size_t)(b * 1024) + n0 + i) * 512 + h * 64 + j0;
        *reinterpret_cast<short8*>(adst)     = a0;
        *reinterpret_cast<short8*>(adst + 8) = a1;
    }
    __syncthreads();
    {
        const int j  = t >> 2;            // d row
        const int i0 = (t & 3) * 16;      // n chunk
        __hip_bfloat16* q = Vt + (((size_t)(b * 8 + h) * 64) + j) * 1024 + n0 + i0;
        short8 v0 = *reinterpret_cast<const short8*>(&lds[j][i0]);
        short8 v1 = *reinterpret_cast<const short8*>(&lds[j][i0 + 8]);
        *reinterpret_cast<short8*>(q)     = v0;
        *reinterpret_cast<short8*>(q + 8) = v1;
    }
}

// ---------------------------------------------------------------------------
// Kernel 2: projection GEMM, all-bf16 inputs.
// C[8192,1024] = Abf[8192,512] @ Wt^T + bias.  64m x 128c tile, block 256.
// Wt panel staged via global_load_lds into slot-major LDS (linear dest,
// <=2-way bank conflicts on b128 reads), double-buffered, 1 barrier/iter.
// grid: (128 mtiles, 8 ctiles, 2 gemms).
// ---------------------------------------------------------------------------
__global__ __launch_bounds__(256, 4) void proj_kernel(
    const __hip_bfloat16* __restrict__ An, const __hip_bfloat16* __restrict__ Ar,
    const __hip_bfloat16* __restrict__ Wtn, const __hip_bfloat16* __restrict__ Wtr,
    const float* __restrict__ bn, const float* __restrict__ br,
    __hip_bfloat16* __restrict__ Qn, __hip_bfloat16* __restrict__ Kn,
    __hip_bfloat16* __restrict__ Qr, __hip_bfloat16* __restrict__ Kr)
{
    const int m0 = blockIdx.x * 64;
    const int c0 = blockIdx.y * 128;
    const int g  = blockIdx.z;
    const __hip_bfloat16* A  = g ? Ar  : An;
    const __hip_bfloat16* Wt = g ? Wtr : Wtn;
    const float* bias = g ? br : bn;
    __hip_bfloat16* Qd = g ? Qr : Qn;
    __hip_bfloat16* Kd = g ? Kr : Kn;

    __shared__ short Bt[2][4][128][8];   // [buf][k-slot][c][8 bf16] = 16KB

    const int t    = threadIdx.x;
    const int lane = t & 63;
    const int w    = t >> 6;
    const int l15  = lane & 15;
    const int lg   = lane >> 4;

    // stage Wt[c0..c0+128][kk..kk+32] -> Bt[buf] (slot-major, linear dest)
    auto stage = [&](int buf, int kk) {
        #pragma unroll
        for (int rep = 0; rep < 2; ++rep) {
            const int u = rep * 256 + t;        // 16B unit 0..511
            const int s = u >> 7;               // k-slot 0..3
            const int c = u & 127;
            const __hip_bfloat16* src = Wt + (size_t)(c0 + c) * 512 + kk + s * 8;
            __builtin_amdgcn_global_load_lds(
                (const __attribute__((address_space(1))) unsigned int*)src,
                (__attribute__((address_space(3))) unsigned int*)&Bt[buf][s][c][0],
                16, 0, 0);
        }
    };

    float4v acc[8] = {};
    const int mrow = m0 + w * 16 + l15;

    stage(0, 0);
    __syncthreads();

    for (int kk = 0; kk < 512; kk += 32) {
        const int buf = (kk >> 5) & 1;
        if (kk < 480) stage(buf ^ 1, kk + 32);
        short8 afrag = *reinterpret_cast<const short8*>(
            A + (size_t)mrow * 512 + kk + lg * 8);
        #pragma unroll
        for (int cs = 0; cs < 8; ++cs) {
            short8 bfrag = *reinterpret_cast<const short8*>(
                &Bt[buf][lg][cs * 16 + l15][0]);
            acc[cs] = MFMA16(afrag, bfrag, acc[cs]);
        }
        __syncthreads();   // drains stage DMA; fences Bt[buf] for next reuse
    }

    // epilogue: bias + scatter to Q/K [b][h][n][64]
    #pragma unroll
    for (int cs = 0; cs < 8; ++cs) {
        const int c  = c0 + cs * 16 + l15;
        const bool isK = (c >= 512);
        const int hh = (c >> 6) & 7;
        const int d  = c & 63;
        __hip_bfloat16* dst = isK ? Kd : Qd;
        const float bv = bias[c];
        #pragma unroll
        for (int r = 0; r < 4; ++r) {
            const int m = m0 + w * 16 + lg * 4 + r;
            const int b = m >> 10, n = m & 1023;
            dst[(((size_t)(b * 8 + hh) * 1024 + n) * 64) + d] =
                __float2bfloat16(acc[cs][r] + bv);
        }
    }
}

// ---------------------------------------------------------------------------
// Kernel 3: attention, softmax over HEADS.  ONE barrier per m-iter.
// grid: (16 combos = b + 8*dir, 16 ntiles of 64 rows), XCD-local.
// block 512 (8 waves): wave = (hg head-pair, iw); each wave covers 2 ns.
// Iter: stage next-K DMA + V loads + K LDS reads issued up front; QK^T + exp
// + psum-write (both ns) -> single __syncthreads (also drains DMA) -> inv,
// P->wave-private LDS, PV.  X_s parity-double-buffered by it&1; K_s dbuf.
// ---------------------------------------------------------------------------
__global__ __launch_bounds__(512, 2) void attn_kernel(
    const __hip_bfloat16* __restrict__ Qn, const __hip_bfloat16* __restrict__ Kn,
    const __hip_bfloat16* __restrict__ Qr, const __hip_bfloat16* __restrict__ Kr,
    const __hip_bfloat16* __restrict__ Vtn, const __hip_bfloat16* __restrict__ Vtr,
    float* __restrict__ out)
{
    const int combo = blockIdx.x;
    const int bb    = combo & 7;
    const int dir   = combo >> 3;
    const int nt    = blockIdx.y;
    const __hip_bfloat16* Q  = dir ? Qr  : Qn;
    const __hip_bfloat16* K  = dir ? Kn  : Kr;
    const __hip_bfloat16* Vt = dir ? Vtn : Vtr;
    float* O = out + (size_t)dir * (8u * 1024u * 512u);

    const int t    = threadIdx.x;
    const int lane = t & 63;
    const int w    = t >> 6;
    const int iw   = w & 1;
    const int hg   = w >> 1;
    const int h0   = hg * 2;
    const int l15  = lane & 15;
    const int lg   = lane >> 4;

    __shared__ short K_s[2][8 * 32 * 64];     // 64KB [buf][h][m][d] swizzled
    __shared__ short P_s[8][32][40];          // 20KB wave-private
    __shared__ float X_s[2][2][4][2][512];    // 32KB [par][ns][hg][iw][p*64+lane]

    const int n0 = nt * 64;
    const float C = 0.125f * 1.44269504f;

    const __hip_bfloat16* Vb[2] = {
        Vt + (size_t)((bb * 8 + h0)     * 64) * 1024,
        Vt + (size_t)((bb * 8 + h0 + 1) * 64) * 1024 };

    auto stage = [&](int bufn, int mt) {
        #pragma unroll
        for (int i = 0; i < 4; ++i) {
            const int u    = (w * 4 + i) * 64 + lane;
            const int h    = u >> 8;
            const int mr   = (u >> 3) & 31;
            const int slot = (u & 7) ^ (mr & 7);
            const __hip_bfloat16* g =
                K + ((size_t)((bb * 8 + h) * 1024) + mt + mr) * 64 + slot * 8;
            __builtin_amdgcn_global_load_lds(
                (const __attribute__((address_space(1))) unsigned int*)g,
                (__attribute__((address_space(3))) unsigned int*)&K_s[bufn][u * 8],
                16, 0, 0);
        }
    };

    short8 qf[2][2][2];
    #pragma unroll
    for (int ns = 0; ns < 2; ++ns)
        #pragma unroll
        for (int hh = 0; hh < 2; ++hh)
            #pragma unroll
            for (int kc = 0; kc < 2; ++kc)
                qf[ns][hh][kc] = *reinterpret_cast<const short8*>(
                    Q + ((size_t)((bb * 8 + h0 + hh) * 1024) + n0 + ns * 32 + iw * 16 + l15) * 64
                      + kc * 32 + lg * 8);

    float4v oacc[2][2][4] = {};

    stage(0, 0);
    __syncthreads();

    for (int it = 0; it < 32; ++it) {
        const int m0  = it << 5;
        const int buf = it & 1;
        const int par = it & 1;
        // ---- issue next-K DMA + V loads as early as possible ----
        stage(buf ^ 1, (it < 31) ? m0 + 32 : 0);
        short8 vf[2][4];
        #pragma unroll
        for (int hh = 0; hh < 2; ++hh)
            #pragma unroll
            for (int dd = 0; dd < 4; ++dd)
                vf[hh][dd] = *reinterpret_cast<const short8*>(
                    Vb[hh] + (size_t)(dd * 16 + l15) * 1024 + m0 + lg * 8);
        // ---- K frags from staged LDS (swizzled slots) ----
        short8 kf[2][2][2];
        const short* ks = K_s[buf];
        #pragma unroll
        for (int hh = 0; hh < 2; ++hh)
            #pragma unroll
            for (int j = 0; j < 2; ++j) {
                const int mr = j * 16 + l15;
                #pragma unroll
                for (int kc = 0; kc < 2; ++kc)
                    kf[hh][j][kc] = *reinterpret_cast<const short8*>(
                        ks + (h0 + hh) * 2048 + mr * 64
                           + (((kc * 4 + lg) ^ (mr & 7)) * 8));
            }
        // ---- QK^T + exp + psum for BOTH ns, then one barrier ----
        float e[2][2][8];
        float ps[2][8];
        #pragma unroll
        for (int ns = 0; ns < 2; ++ns) {
            float4v sacc[2][2] = {};
            #pragma unroll
            for (int hh = 0; hh < 2; ++hh)
                #pragma unroll
                for (int j = 0; j < 2; ++j)
                    #pragma unroll
                    for (int kc = 0; kc < 2; ++kc)
                        sacc[hh][j] = MFMA16(kf[hh][j][kc], qf[ns][hh][kc], sacc[hh][j]);
            #pragma unroll
            for (int p = 0; p < 8; ++p) ps[ns][p] = 0.f;
            #pragma unroll
            for (int hh = 0; hh < 2; ++hh)
                #pragma unroll
                for (int j = 0; j < 2; ++j)
                    #pragma unroll
                    for (int r = 0; r < 4; ++r) {
                        float ev = exp2f(sacc[hh][j][r] * C);
                        e[ns][hh][j * 4 + r] = ev;
                        ps[ns][j * 4 + r] += ev;
                    }
            #pragma unroll
            for (int p = 0; p < 8; ++p)
                X_s[par][ns][hg][iw][p * 64 + lane] = ps[ns][p];
        }
        __syncthreads();   // the ONLY barrier: X visible + K DMA drained
        // ---- inv, P, PV ----
        #pragma unroll
        for (int ns = 0; ns < 2; ++ns) {
            float inv[8];
            #pragma unroll
            for (int p = 0; p < 8; ++p) {
                float tot = ps[ns][p];
                #pragma unroll
                for (int g = 1; g < 4; ++g)
                    tot += X_s[par][ns][(hg + g) & 3][iw][p * 64 + lane];
                inv[p] = __builtin_amdgcn_rcpf(tot);
            }
            #pragma unroll
            for (int hh = 0; hh < 2; ++hh)
                #pragma unroll
                for (int j = 0; j < 2; ++j) {
                    short4v pk;
                    #pragma unroll
                    for (int r = 0; r < 4; ++r)
                        pk[r] = f2bf(e[ns][hh][j * 4 + r] * inv[j * 4 + r]);
                    *reinterpret_cast<short4v*>(
                        &P_s[h0 + hh][iw * 16 + l15][j * 16 + lg * 4]) = pk;
                }
            #pragma unroll
            for (int hh = 0; hh < 2; ++hh) {
                short8 pf = *reinterpret_cast<const short8*>(
                    &P_s[h0 + hh][iw * 16 + l15][lg * 8]);
                #pragma unroll
                for (int dd = 0; dd < 4; ++dd)
                    oacc[ns][hh][dd] = MFMA16(pf, vf[hh][dd], oacc[ns][hh][dd]);
            }
        }
    }

    // ---- epilogue: O[b][n][h*64+d] f32 ----
    #pragma unroll
    for (int ns = 0; ns < 2; ++ns)
        #pragma unroll
        for (int hh = 0; hh < 2; ++hh)
            #pragma unroll
            for (int dd = 0; dd < 4; ++dd)
                #pragma unroll
                for (int r = 0; r < 4; ++r) {
                    const int n = n0 + ns * 32 + iw * 16 + lg * 4 + r;
                    const int d = dd * 16 + l15;
                    O[((size_t)(bb * 1024) + n) * 512 + (h0 + hh) * 64 + d] =
                        oacc[ns][hh][dd][r];
                }
}

extern "C" void kernel_launch(void* const* d_in, const int* in_sizes, int n_in,
                              void* d_out, int out_size, void* d_ws, size_t ws_size,
                              hipStream_t stream) {
    const float* nv = (const float*)d_in[0];
    const float* rv = (const float*)d_in[1];
    const float* Wn = (const float*)d_in[2];
    const float* bn = (const float*)d_in[3];
    const float* Wr = (const float*)d_in[4];
    const float* br = (const float*)d_in[5];
    float* out = (float*)d_out;

    __hip_bfloat16* w = (__hip_bfloat16*)d_ws;
    const size_t E = 8ull * 8 * 1024 * 64;    // 4M elems
    __hip_bfloat16* Qn  = w;
    __hip_bfloat16* Kn  = w + E;
    __hip_bfloat16* Qr  = w + 2 * E;
    __hip_bfloat16* Kr  = w + 3 * E;
    __hip_bfloat16* Vtn = w + 4 * E;
    __hip_bfloat16* Vtr = w + 5 * E;
    __hip_bfloat16* An  = w + 6 * E;
    __hip_bfloat16* Ar  = w + 7 * E;
    __hip_bfloat16* Wtn = w + 8 * E;
    __hip_bfloat16* Wtr = w + 8 * E + 512 * 1024;

    wt_kernel  <<<dim3(16, 8, 2), 256, 0, stream>>>(Wn, Wr, Wtn, Wtr);
    prep_kernel<<<dim3(32, 8, 8), 256, 0, stream>>>(nv, rv, Vtn, Vtr, An, Ar);
    proj_kernel<<<dim3(128, 8, 2), 256, 0, stream>>>(An, Ar, Wtn, Wtr, bn, br,
                                                     Qn, Kn, Qr, Kr);
    attn_kernel<<<dim3(16, 16), 512, 0, stream>>>(Qn, Kn, Qr, Kr, Vtn, Vtr, out);
}